// Round 6
// baseline (56.486 us; speedup 1.0000x reference)
//
#include <hip/hip_runtime.h>
#include <math.h>

#define U 128
#define NIT 20   // fixed Picard iterations per layer (ρ≈0.35 → err < 1e-6 ≪ bf16 noise floor)

typedef __attribute__((ext_vector_type(8))) short bf16x8;
typedef __attribute__((ext_vector_type(4))) float f32x4;

__device__ inline unsigned int pack2(float a, float b) {
    // low short = bf16(a) (truncated), high short = bf16(b)
    return (__float_as_uint(a) >> 16) | (__float_as_uint(b) & 0xFFFF0000u);
}
__device__ inline float lo_of(float a) {
    return a - __uint_as_float(__float_as_uint(a) & 0xFFFF0000u);
}
__device__ inline float fromhi(unsigned short h) {
    return __uint_as_float(((unsigned int)h) << 16);
}
__device__ inline float tanh_fast(float v) {
    float e = __expf(2.0f * v);
    return 1.0f - 2.0f / (e + 1.0f);
}
#define MFMA(A, B, C) __builtin_amdgcn_mfma_f32_16x16x32_bf16(A, B, C, 0, 0, 0)

// ---------------------------------------------------------------------------
// k_split: elementwise f32 -> (trunc-bf16 hi, bf16 lo) for X, Wi, Wb.
// ---------------------------------------------------------------------------
__global__ __launch_bounds__(256) void k_split(
        const float* __restrict__ X, const float* __restrict__ Wi,
        const float* __restrict__ Wb,
        unsigned short* __restrict__ Xh, unsigned short* __restrict__ Xl,
        unsigned short* __restrict__ Wih, unsigned short* __restrict__ Wil,
        unsigned short* __restrict__ Wbh, unsigned short* __restrict__ Wbl,
        int n4X, int n4Wi, int n4Wb) {
    int i = blockIdx.x * blockDim.x + threadIdx.x;
    const float* src;
    unsigned short *dh, *dl;
    int j;
    if (i < n4X)                    { j = i;               src = X;  dh = Xh;  dl = Xl;  }
    else if (i < n4X + n4Wi)        { j = i - n4X;         src = Wi; dh = Wih; dl = Wil; }
    else if (i < n4X + n4Wi + n4Wb) { j = i - n4X - n4Wi;  src = Wb; dh = Wbh; dl = Wbl; }
    else return;
    float4 v = *(const float4*)&src[(long)j * 4];
    uint2 hh, ll;
    hh.x = pack2(v.x, v.y);               hh.y = pack2(v.z, v.w);
    ll.x = pack2(lo_of(v.x), lo_of(v.y)); ll.y = pack2(lo_of(v.z), lo_of(v.w));
    *(uint2*)&dh[(long)j * 4] = hh;
    *(uint2*)&dl[(long)j * 4] = ll;
}

// ---------------------------------------------------------------------------
// k_all: fully fused network, swapped-operand MFMA, FIXED iteration count.
// grid = B/16, 512 threads (8 waves). Block owns 16 batch rows; wave w owns
// cols 16w..16w+15.
//
// Swapped MFMA: D = A·B, A = W-frag (m = out col), B = z^T-frag (n = row).
// C/D => lane l15 = batch row, reg i = col 16w+4lq+i (row-major per lane:
// one uint2 LDS write for hi, one for lo).
// LDS z: byte(r,c) = r*256 + ((2c) ^ ((r&7)<<4))  XOR swizzle.
// No convergence check: NIT fixed => no shuffle reduce, no consensus LDS,
// no branch; loop unrolls with compile-time buffer parity.
// ---------------------------------------------------------------------------
__global__ __launch_bounds__(512) void k_all(
        const unsigned short* __restrict__ Xh, const unsigned short* __restrict__ Xl,
        const unsigned short* __restrict__ Wih, const unsigned short* __restrict__ Wil,
        const unsigned short* __restrict__ Wbh, const unsigned short* __restrict__ Wbl,
        const float* __restrict__ bi,
        const float* __restrict__ Wo, const float* __restrict__ bo,
        float* __restrict__ Out, int L) {
    __shared__ unsigned short zhS[2][16 * U];   // 8 KB hi (double-buffered)
    __shared__ unsigned short zlS[2][16 * U];   // 8 KB lo

    const int tid  = threadIdx.x;
    const int w    = tid >> 6;
    const int lane = tid & 63;
    const int l15  = lane & 15;
    const int lq   = lane >> 4;
    const int r0   = blockIdx.x * 16;
    const int colA = w * 16 + l15;     // W row for A-frags (= output col)
    const int KD   = 784;

    // ---------------- Phase 1: x = X @ Wi^T + bi (swapped) ----------------
    float4 bi4 = *(const float4*)&bi[w * 16 + lq * 4];
    f32x4 a0 = {bi4.x, bi4.y, bi4.z, bi4.w};
    f32x4 a1 = {0.f, 0.f, 0.f, 0.f};
    f32x4 a2 = {0.f, 0.f, 0.f, 0.f};
    {
        const unsigned short* xhp = &Xh[(long)(r0 + l15) * KD];
        const unsigned short* xlp = &Xl[(long)(r0 + l15) * KD];
        const unsigned short* whp = &Wih[(long)colA * KD];
        const unsigned short* wlp = &Wil[(long)colA * KD];
        #pragma unroll 4
        for (int kc = 0; kc < 24; ++kc) {
            const int k = kc * 32 + lq * 8;
            bf16x8 ah = *(const bf16x8*)&xhp[k];
            bf16x8 al = *(const bf16x8*)&xlp[k];
            bf16x8 bh = *(const bf16x8*)&whp[k];
            bf16x8 bl = *(const bf16x8*)&wlp[k];
            a0 = MFMA(bh, ah, a0);     // Wh . xh
            a1 = MFMA(bh, al, a1);     // Wh . xl
            a2 = MFMA(bl, ah, a2);     // Wl . xh
        }
        bf16x8 ah = {0,0,0,0,0,0,0,0}, al = ah, bh = ah, bl = ah;
        if (lq < 2) {
            const int k = 768 + lq * 8;
            ah = *(const bf16x8*)&xhp[k];
            al = *(const bf16x8*)&xlp[k];
            bh = *(const bf16x8*)&whp[k];
            bl = *(const bf16x8*)&wlp[k];
        }
        a0 = MFMA(bh, ah, a0);
        a1 = MFMA(bh, al, a1);
        a2 = MFMA(bl, ah, a2);
    }
    // lane l15 = batch row, reg i = col 16w+4lq+i
    float xf[4], zr[4];
    #pragma unroll
    for (int i = 0; i < 4; ++i) xf[i] = a0[i] + a1[i] + a2[i];

    // ---------------- Phase 2: Picard layers (fixed NIT) ----------------
    const int swz = (l15 & 7) << 4;
    int offA[4];
    #pragma unroll
    for (int ks = 0; ks < 4; ++ks)
        offA[ks] = l15 * 256 + ((64 * ks + 16 * lq) ^ swz);
    const int offWr = l15 * 256 + ((32 * w + 8 * lq) ^ swz);

    char* zhB = (char*)&zhS[0][0];
    char* zlB = (char*)&zlS[0][0];

    for (int l = 0; l < L; ++l) {
        // layer weights -> registers (A-frag: row = colA, k contiguous)
        bf16x8 whf[4], wlf[4];
        {
            const unsigned short* wbh = &Wbh[((long)l * U + colA) * U];
            const unsigned short* wbl = &Wbl[((long)l * U + colA) * U];
            #pragma unroll
            for (int ks = 0; ks < 4; ++ks) {
                const int k = ks * 32 + lq * 8;
                whf[ks] = *(const bf16x8*)&wbh[k];
                wlf[ks] = *(const bf16x8*)&wbl[k];
            }
        }

        // z0 = tanh(x) -> buffer 0
        {
            uint2 hh, ll;
            #pragma unroll
            for (int i = 0; i < 4; ++i) { zr[i] = tanh_fast(xf[i]); }
            hh.x = pack2(zr[0], zr[1]); hh.y = pack2(zr[2], zr[3]);
            ll.x = pack2(lo_of(zr[0]), lo_of(zr[1]));
            ll.y = pack2(lo_of(zr[2]), lo_of(zr[3]));
            *(uint2*)(zhB + offWr) = hh;
            *(uint2*)(zlB + offWr) = ll;
        }
        __syncthreads();

        #pragma unroll 2
        for (int it = 0; it < NIT; ++it) {
            const int cur = it & 1;
            const int nxt = cur ^ 1;
            bf16x8 zhf[4], zlf[4];
            #pragma unroll
            for (int ks = 0; ks < 4; ++ks) {
                zhf[ks] = *(const bf16x8*)(zhB + cur * 4096 + offA[ks]);
                zlf[ks] = *(const bf16x8*)(zlB + cur * 4096 + offA[ks]);
            }

            // 6 independent accumulator chains (depth 2 each)
            f32x4 b0a = {xf[0], xf[1], xf[2], xf[3]};
            f32x4 b0b = {0.f, 0.f, 0.f, 0.f};
            f32x4 b1a = b0b, b1b = b0b, b2a = b0b, b2b = b0b;
            b0a = MFMA(whf[0], zhf[0], b0a);
            b1a = MFMA(whf[0], zlf[0], b1a);
            b2a = MFMA(wlf[0], zhf[0], b2a);
            b0b = MFMA(whf[2], zhf[2], b0b);
            b1b = MFMA(whf[2], zlf[2], b1b);
            b2b = MFMA(wlf[2], zhf[2], b2b);
            b0a = MFMA(whf[1], zhf[1], b0a);
            b1a = MFMA(whf[1], zlf[1], b1a);
            b2a = MFMA(wlf[1], zhf[1], b2a);
            b0b = MFMA(whf[3], zhf[3], b0b);
            b1b = MFMA(whf[3], zlf[3], b1b);
            b2b = MFMA(wlf[3], zhf[3], b2b);

            #pragma unroll
            for (int i = 0; i < 4; ++i)
                zr[i] = tanh_fast(b0a[i] + b0b[i] + b1a[i] + b1b[i]
                                + b2a[i] + b2b[i]);
            uint2 hh, ll;
            hh.x = pack2(zr[0], zr[1]); hh.y = pack2(zr[2], zr[3]);
            ll.x = pack2(lo_of(zr[0]), lo_of(zr[1]));
            ll.y = pack2(lo_of(zr[2]), lo_of(zr[3]));
            *(uint2*)(zhB + nxt * 4096 + offWr) = hh;
            *(uint2*)(zlB + nxt * 4096 + offWr) = ll;
            __syncthreads();
        }
        #pragma unroll
        for (int i = 0; i < 4; ++i) xf[i] = zr[i];   // next layer input
    }
    // NIT even => final z is in buffer 0 (last write at it=NIT-1 -> nxt=0)

    // ---------------- Phase 3: output GEMM + softmax ----------------
    const char* zhF = zhB;
    const char* zlF = zlB;
    #pragma unroll
    for (int rr2 = 0; rr2 < 2; ++rr2) {
        const int rrow = 2 * w + rr2;
        const int o1 = rrow * 256 + ((lane * 2) ^ ((rrow & 7) << 4));
        const int o2 = rrow * 256 + (((lane + 64) * 2) ^ ((rrow & 7) << 4));
        const float zv0 = fromhi(*(const unsigned short*)(zhF + o1))
                        + fromhi(*(const unsigned short*)(zlF + o1));
        const float zv1 = fromhi(*(const unsigned short*)(zhF + o2))
                        + fromhi(*(const unsigned short*)(zlF + o2));
        float e[10];
        float m = -1e30f;
        #pragma unroll
        for (int o = 0; o < 10; ++o) {
            float p = zv0 * Wo[o * U + lane] + zv1 * Wo[o * U + 64 + lane];
            #pragma unroll
            for (int off = 32; off > 0; off >>= 1)
                p += __shfl_xor(p, off);
            p += bo[o];
            e[o] = p;
            m = fmaxf(m, p);
        }
        float s = 0.f;
        #pragma unroll
        for (int o = 0; o < 10; ++o) {
            e[o] = __expf(e[o] - m);
            s += e[o];
        }
        const float inv = 1.0f / s;
        float v = 0.f;
        #pragma unroll
        for (int o = 0; o < 10; ++o)
            if (lane == o) v = e[o] * inv;
        if (lane < 10) Out[(long)(r0 + rrow) * 10 + lane] = v;
    }
}

// ---------------------------------------------------------------------------
extern "C" void kernel_launch(void* const* d_in, const int* in_sizes, int n_in,
                              void* d_out, int out_size, void* d_ws, size_t ws_size,
                              hipStream_t stream) {
    const float* x  = (const float*)d_in[0];   // [B,784]
    const float* Wi = (const float*)d_in[1];   // [128,784]
    const float* bi = (const float*)d_in[2];   // [128]
    const float* Wb = (const float*)d_in[3];   // [L,128,128]
    const float* Wo = (const float*)d_in[4];   // [10,128]
    const float* bo = (const float*)d_in[5];   // [10]
    float* out = (float*)d_out;

    const int DIN = 784;
    const int B   = in_sizes[0] / DIN;             // 2048
    const int L   = in_sizes[3] / (U * U);         // 2

    const long nX  = (long)B * DIN;
    const long nWi = (long)U * DIN;
    const long nWb = (long)L * U * U;

    unsigned short* Xh  = (unsigned short*)d_ws;
    unsigned short* Xl  = Xh  + nX;
    unsigned short* Wih = Xl  + nX;
    unsigned short* Wil = Wih + nWi;
    unsigned short* WbhP= Wil + nWi;
    unsigned short* WblP= WbhP + nWb;

    const int n4X  = (int)(nX  / 4);
    const int n4Wi = (int)(nWi / 4);
    const int n4Wb = (int)(nWb / 4);
    const int tot4 = n4X + n4Wi + n4Wb;

    k_split<<<(tot4 + 255) / 256, 256, 0, stream>>>(
        x, Wi, Wb, Xh, Xl, Wih, Wil, WbhP, WblP, n4X, n4Wi, n4Wb);

    k_all<<<B / 16, 512, 0, stream>>>(
        Xh, Xl, Wih, Wil, WbhP, WblP, bi, Wo, bo, out, L);
}

// Round 7
// 53.080 us; speedup vs baseline: 1.0642x; 1.0642x over previous
//
#include <hip/hip_runtime.h>
#include <math.h>

#define U 128
#define NIT 20   // fixed Picard iterations per layer (ρ≈0.35 → err < 1e-6 ≪ bf16 noise floor)

typedef __attribute__((ext_vector_type(8))) short bf16x8;
typedef __attribute__((ext_vector_type(4))) float f32x4;

__device__ inline unsigned int pack2(float a, float b) {
    // low short = bf16(a) (truncated), high short = bf16(b)
    return (__float_as_uint(a) >> 16) | (__float_as_uint(b) & 0xFFFF0000u);
}
__device__ inline float lo_of(float a) {
    return a - __uint_as_float(__float_as_uint(a) & 0xFFFF0000u);
}
__device__ inline float fromhi(unsigned short h) {
    return __uint_as_float(((unsigned int)h) << 16);
}
__device__ inline float tanh_fast(float v) {
    float e = __expf(2.0f * v);
    return 1.0f - 2.0f / (e + 1.0f);
}
#define MFMA(A, B, C) __builtin_amdgcn_mfma_f32_16x16x32_bf16(A, B, C, 0, 0, 0)

// ---------------------------------------------------------------------------
// k_stage: f32 -> (trunc-bf16 hi, bf16 lo). Blocks 0..127 handle X slab b
// (rows 16b..16b+15) so the slab lands in the same XCD L2 that k_gemm_in /
// k_picard block b (mod 8 round-robin heuristic) will read from. Blocks
// 128..159 grid-stride Wi then Wb.
// ---------------------------------------------------------------------------
__global__ __launch_bounds__(512) void k_stage(
        const float* __restrict__ X, const float* __restrict__ Wi,
        const float* __restrict__ Wb,
        unsigned short* __restrict__ Xh, unsigned short* __restrict__ Xl,
        unsigned short* __restrict__ Wih, unsigned short* __restrict__ Wil,
        unsigned short* __restrict__ Wbh, unsigned short* __restrict__ Wbl,
        int n4Wi, int n4Wb) {
    const int b = blockIdx.x, t = threadIdx.x;
    if (b < 128) {
        const int base = b * 3136;                 // 16 rows * 784 / 4 quads
        #pragma unroll 2
        for (int q = t; q < 3136; q += 512) {
            const long j = (long)(base + q) * 4;
            float4 v = *(const float4*)&X[j];
            uint2 hh, ll;
            hh.x = pack2(v.x, v.y);               hh.y = pack2(v.z, v.w);
            ll.x = pack2(lo_of(v.x), lo_of(v.y)); ll.y = pack2(lo_of(v.z), lo_of(v.w));
            *(uint2*)&Xh[j] = hh;
            *(uint2*)&Xl[j] = ll;
        }
    } else {
        const int tot = n4Wi + n4Wb;
        for (int q = (b - 128) * 512 + t; q < tot; q += 32 * 512) {
            const float* src;
            unsigned short *dh, *dl;
            long j;
            if (q < n4Wi) { j = (long)q * 4;            src = Wi; dh = Wih; dl = Wil; }
            else          { j = (long)(q - n4Wi) * 4;   src = Wb; dh = Wbh; dl = Wbl; }
            float4 v = *(const float4*)&src[j];
            uint2 hh, ll;
            hh.x = pack2(v.x, v.y);               hh.y = pack2(v.z, v.w);
            ll.x = pack2(lo_of(v.x), lo_of(v.y)); ll.y = pack2(lo_of(v.z), lo_of(v.w));
            *(uint2*)&dh[j] = hh;
            *(uint2*)&dl[j] = ll;
        }
    }
}

// ---------------------------------------------------------------------------
// k_gemm_in: zA = X @ Wi^T + bi  (f32 out), swapped-operand MFMA, 3-term
// bf16 split, SPLIT-K=2 across waves.
// grid: 256 blocks (slab = bid&127, ch = bid>>7), 512 threads.
// wave w: ct = w&3 (16-col tile within 64-col half), kh = w>>2 (K half).
//   kh=0: k in [0,384), C-init = bias;  kh=1: k in [384,784), C-init = 0.
// Cross-K reduce via LDS; kh=0 waves store f32 result.
// Dedicated kernel => regalloc free to pipeline the ~50 b128 loads/lane.
// ---------------------------------------------------------------------------
__global__ __launch_bounds__(512) void k_gemm_in(
        const unsigned short* __restrict__ Xh, const unsigned short* __restrict__ Xl,
        const unsigned short* __restrict__ Wih, const unsigned short* __restrict__ Wil,
        const float* __restrict__ bi, float* __restrict__ zA) {
    __shared__ f32x4 redS[4][64];
    const int tid  = threadIdx.x;
    const int w    = tid >> 6;
    const int lane = tid & 63;
    const int l15  = lane & 15;
    const int lq   = lane >> 4;
    const int slab = blockIdx.x & 127;
    const int ch   = blockIdx.x >> 7;
    const int ct   = w & 3;
    const int kh   = w >> 2;
    const int r0   = slab * 16;
    const int cb   = ch * 64 + ct * 16;      // col-tile base
    const int colA = cb + l15;               // Wi row (= output col) for A-frag
    const int KD   = 784;

    const unsigned short* xhp = &Xh[(long)(r0 + l15) * KD];
    const unsigned short* xlp = &Xl[(long)(r0 + l15) * KD];
    const unsigned short* whp = &Wih[(long)colA * KD];
    const unsigned short* wlp = &Wil[(long)colA * KD];

    f32x4 a0 = {0.f, 0.f, 0.f, 0.f};
    f32x4 a1 = {0.f, 0.f, 0.f, 0.f};
    f32x4 a2 = {0.f, 0.f, 0.f, 0.f};
    if (kh == 0) {
        float4 b4 = *(const float4*)&bi[cb + lq * 4];
        a0[0] = b4.x; a0[1] = b4.y; a0[2] = b4.z; a0[3] = b4.w;
    }

    const int kbase = kh ? 384 : 0;
    #pragma unroll 6
    for (int c = 0; c < 12; ++c) {
        const int k = kbase + c * 32 + lq * 8;
        bf16x8 ah = *(const bf16x8*)&xhp[k];
        bf16x8 al = *(const bf16x8*)&xlp[k];
        bf16x8 bh = *(const bf16x8*)&whp[k];
        bf16x8 bl = *(const bf16x8*)&wlp[k];
        a0 = MFMA(bh, ah, a0);     // Wh . xh
        a1 = MFMA(bh, al, a1);     // Wh . xl
        a2 = MFMA(bl, ah, a2);     // Wl . xh
    }
    if (kh) {   // half chunk k = 768..783 (valid lq<2)
        bf16x8 ah = {0,0,0,0,0,0,0,0}, al = ah, bh = ah, bl = ah;
        if (lq < 2) {
            const int k = 768 + lq * 8;
            ah = *(const bf16x8*)&xhp[k];
            al = *(const bf16x8*)&xlp[k];
            bh = *(const bf16x8*)&whp[k];
            bl = *(const bf16x8*)&wlp[k];
        }
        a0 = MFMA(bh, ah, a0);
        a1 = MFMA(bh, al, a1);
        a2 = MFMA(bl, ah, a2);
    }

    f32x4 r;
    #pragma unroll
    for (int i = 0; i < 4; ++i) r[i] = a0[i] + a1[i] + a2[i];

    if (kh) redS[ct][lane] = r;
    __syncthreads();
    if (!kh) {
        f32x4 o = redS[ct][lane];
        float4 st;
        st.x = r[0] + o[0]; st.y = r[1] + o[1];
        st.z = r[2] + o[2]; st.w = r[3] + o[3];
        // lane l15 = batch row, regs = cols cb+4lq..+3
        *(float4*)&zA[(long)(r0 + l15) * U + cb + lq * 4] = st;
    }
}

// ---------------------------------------------------------------------------
// k_picard: Picard layers + output GEMM + softmax (phases 2+3 of R6 k_all).
// grid: B/16 blocks, 512 threads (8 waves). Wave w owns cols 16w..16w+15.
// LDS z: byte(r,c) = r*256 + ((2c) ^ ((r&7)<<4))  XOR swizzle.
// ---------------------------------------------------------------------------
__global__ __launch_bounds__(512) void k_picard(
        const float* __restrict__ zA,
        const unsigned short* __restrict__ Wbh, const unsigned short* __restrict__ Wbl,
        const float* __restrict__ Wo, const float* __restrict__ bo,
        float* __restrict__ Out, int L) {
    __shared__ unsigned short zhS[2][16 * U];   // 8 KB hi (double-buffered)
    __shared__ unsigned short zlS[2][16 * U];   // 8 KB lo

    const int tid  = threadIdx.x;
    const int w    = tid >> 6;
    const int lane = tid & 63;
    const int l15  = lane & 15;
    const int lq   = lane >> 4;
    const int r0   = blockIdx.x * 16;
    const int colA = w * 16 + l15;     // W row for A-frags (= output col)

    // x (z-lin) from k_gemm_in: lane l15 = batch row, reg i = col 16w+4lq+i
    float xf[4], zr[4];
    {
        float4 x4 = *(const float4*)&zA[(long)(r0 + l15) * U + w * 16 + lq * 4];
        xf[0] = x4.x; xf[1] = x4.y; xf[2] = x4.z; xf[3] = x4.w;
    }

    const int swz = (l15 & 7) << 4;
    int offA[4];
    #pragma unroll
    for (int ks = 0; ks < 4; ++ks)
        offA[ks] = l15 * 256 + ((64 * ks + 16 * lq) ^ swz);
    const int offWr = l15 * 256 + ((32 * w + 8 * lq) ^ swz);

    char* zhB = (char*)&zhS[0][0];
    char* zlB = (char*)&zlS[0][0];

    for (int l = 0; l < L; ++l) {
        bf16x8 whf[4], wlf[4];
        {
            const unsigned short* wbh = &Wbh[((long)l * U + colA) * U];
            const unsigned short* wbl = &Wbl[((long)l * U + colA) * U];
            #pragma unroll
            for (int ks = 0; ks < 4; ++ks) {
                const int k = ks * 32 + lq * 8;
                whf[ks] = *(const bf16x8*)&wbh[k];
                wlf[ks] = *(const bf16x8*)&wbl[k];
            }
        }

        // z0 = tanh(x) -> buffer 0
        {
            uint2 hh, ll;
            #pragma unroll
            for (int i = 0; i < 4; ++i) { zr[i] = tanh_fast(xf[i]); }
            hh.x = pack2(zr[0], zr[1]); hh.y = pack2(zr[2], zr[3]);
            ll.x = pack2(lo_of(zr[0]), lo_of(zr[1]));
            ll.y = pack2(lo_of(zr[2]), lo_of(zr[3]));
            *(uint2*)(zhB + offWr) = hh;
            *(uint2*)(zlB + offWr) = ll;
        }
        __syncthreads();

        #pragma unroll 2
        for (int it = 0; it < NIT; ++it) {
            const int cur = it & 1;
            const int nxt = cur ^ 1;
            bf16x8 zhf[4], zlf[4];
            #pragma unroll
            for (int ks = 0; ks < 4; ++ks) {
                zhf[ks] = *(const bf16x8*)(zhB + cur * 4096 + offA[ks]);
                zlf[ks] = *(const bf16x8*)(zlB + cur * 4096 + offA[ks]);
            }

            f32x4 b0a = {xf[0], xf[1], xf[2], xf[3]};
            f32x4 b0b = {0.f, 0.f, 0.f, 0.f};
            f32x4 b1a = b0b, b1b = b0b, b2a = b0b, b2b = b0b;
            b0a = MFMA(whf[0], zhf[0], b0a);
            b1a = MFMA(whf[0], zlf[0], b1a);
            b2a = MFMA(wlf[0], zhf[0], b2a);
            b0b = MFMA(whf[2], zhf[2], b0b);
            b1b = MFMA(whf[2], zlf[2], b1b);
            b2b = MFMA(wlf[2], zhf[2], b2b);
            b0a = MFMA(whf[1], zhf[1], b0a);
            b1a = MFMA(whf[1], zlf[1], b1a);
            b2a = MFMA(wlf[1], zhf[1], b2a);
            b0b = MFMA(whf[3], zhf[3], b0b);
            b1b = MFMA(whf[3], zlf[3], b1b);
            b2b = MFMA(wlf[3], zhf[3], b2b);

            #pragma unroll
            for (int i = 0; i < 4; ++i)
                zr[i] = tanh_fast(b0a[i] + b0b[i] + b1a[i] + b1b[i]
                                + b2a[i] + b2b[i]);
            uint2 hh, ll;
            hh.x = pack2(zr[0], zr[1]); hh.y = pack2(zr[2], zr[3]);
            ll.x = pack2(lo_of(zr[0]), lo_of(zr[1]));
            ll.y = pack2(lo_of(zr[2]), lo_of(zr[3]));
            *(uint2*)(zhB + nxt * 4096 + offWr) = hh;
            *(uint2*)(zlB + nxt * 4096 + offWr) = ll;
            __syncthreads();
        }
        #pragma unroll
        for (int i = 0; i < 4; ++i) xf[i] = zr[i];
    }
    // NIT even => final z in buffer 0

    // ---------------- output GEMM + softmax ----------------
    #pragma unroll
    for (int rr2 = 0; rr2 < 2; ++rr2) {
        const int rrow = 2 * w + rr2;
        const int o1 = rrow * 256 + ((lane * 2) ^ ((rrow & 7) << 4));
        const int o2 = rrow * 256 + (((lane + 64) * 2) ^ ((rrow & 7) << 4));
        const float zv0 = fromhi(*(const unsigned short*)(zhB + o1))
                        + fromhi(*(const unsigned short*)(zlB + o1));
        const float zv1 = fromhi(*(const unsigned short*)(zhB + o2))
                        + fromhi(*(const unsigned short*)(zlB + o2));
        float e[10];
        float m = -1e30f;
        #pragma unroll
        for (int o = 0; o < 10; ++o) {
            float p = zv0 * Wo[o * U + lane] + zv1 * Wo[o * U + 64 + lane];
            #pragma unroll
            for (int off = 32; off > 0; off >>= 1)
                p += __shfl_xor(p, off);
            p += bo[o];
            e[o] = p;
            m = fmaxf(m, p);
        }
        float s = 0.f;
        #pragma unroll
        for (int o = 0; o < 10; ++o) {
            e[o] = __expf(e[o] - m);
            s += e[o];
        }
        const float inv = 1.0f / s;
        float v = 0.f;
        #pragma unroll
        for (int o = 0; o < 10; ++o)
            if (lane == o) v = e[o] * inv;
        if (lane < 10) Out[(long)(r0 + rrow) * 10 + lane] = v;
    }
}

// ---------------------------------------------------------------------------
extern "C" void kernel_launch(void* const* d_in, const int* in_sizes, int n_in,
                              void* d_out, int out_size, void* d_ws, size_t ws_size,
                              hipStream_t stream) {
    const float* x  = (const float*)d_in[0];   // [B,784]
    const float* Wi = (const float*)d_in[1];   // [128,784]
    const float* bi = (const float*)d_in[2];   // [128]
    const float* Wb = (const float*)d_in[3];   // [L,128,128]
    const float* Wo = (const float*)d_in[4];   // [10,128]
    const float* bo = (const float*)d_in[5];   // [10]
    float* out = (float*)d_out;

    const int DIN = 784;
    const int B   = in_sizes[0] / DIN;             // 2048
    const int L   = in_sizes[3] / (U * U);         // 2

    const long nX  = (long)B * DIN;
    const long nWi = (long)U * DIN;
    const long nWb = (long)L * U * U;

    unsigned short* Xh  = (unsigned short*)d_ws;
    unsigned short* Xl  = Xh  + nX;
    unsigned short* Wih = Xl  + nX;
    unsigned short* Wil = Wih + nWi;
    unsigned short* WbhP= Wil + nWi;
    unsigned short* WblP= WbhP + nWb;
    float*          zA  = (float*)(WblP + nWb);    // [B,U] f32 (16B-aligned)

    const int n4Wi = (int)(nWi / 4);
    const int n4Wb = (int)(nWb / 4);

    k_stage<<<160, 512, 0, stream>>>(x, Wi, Wb, Xh, Xl, Wih, Wil, WbhP, WblP,
                                     n4Wi, n4Wb);
    k_gemm_in<<<256, 512, 0, stream>>>(Xh, Xl, Wih, Wil, bi, zA);
    k_picard<<<B / 16, 512, 0, stream>>>(zA, WbhP, WblP, Wo, bo, out, L);
}

// Round 9
// 36.650 us; speedup vs baseline: 1.5412x; 1.4483x over previous
//
#include <hip/hip_runtime.h>
#include <math.h>

#define U 128
#define NIT 16   // fixed Picard iterations per layer (even; ρ≤0.75 → z err ≲1e-3)

typedef __attribute__((ext_vector_type(8))) short bf16x8;
typedef __attribute__((ext_vector_type(4))) float f32x4;
typedef __attribute__((ext_vector_type(4))) unsigned int u32x4;

__device__ inline unsigned int pack2(float a, float b) {
    // low short = bf16(a) (truncated), high short = bf16(b)
    return (__float_as_uint(a) >> 16) | (__float_as_uint(b) & 0xFFFF0000u);
}
__device__ inline float lo_of(float a) {
    return a - __uint_as_float(__float_as_uint(a) & 0xFFFF0000u);
}
__device__ inline unsigned int packrn(float a, float b) {
    // RTNE pack: low = bf16_rn(a), high = bf16_rn(b). No builtin on gfx950
    // (m240) -> inline asm v_cvt_pk_bf16_f32.
    unsigned int r;
    asm("v_cvt_pk_bf16_f32 %0, %1, %2" : "=v"(r) : "v"(a), "v"(b));
    return r;
}
__device__ inline float fromhi(unsigned short h) {
    return __uint_as_float(((unsigned int)h) << 16);
}
__device__ inline float tanh_fast(float v) {
    float e = __expf(2.0f * v);
    return 1.0f - 2.0f / (e + 1.0f);
}
#define MFMA(A, B, C) __builtin_amdgcn_mfma_f32_16x16x32_bf16(A, B, C, 0, 0, 0)

// in-register f32 -> (trunc-bf16 hi, bf16 lo) split of 8 values
#define SPLIT8(P4, Q4, H, LO)                                              \
{   u32x4 h_, l_;                                                          \
    h_[0] = pack2(P4.x, P4.y); h_[1] = pack2(P4.z, P4.w);                  \
    h_[2] = pack2(Q4.x, Q4.y); h_[3] = pack2(Q4.z, Q4.w);                  \
    l_[0] = pack2(lo_of(P4.x), lo_of(P4.y));                               \
    l_[1] = pack2(lo_of(P4.z), lo_of(P4.w));                               \
    l_[2] = pack2(lo_of(Q4.x), lo_of(Q4.y));                               \
    l_[3] = pack2(lo_of(Q4.z), lo_of(Q4.w));                               \
    H  = __builtin_bit_cast(bf16x8, h_);                                   \
    LO = __builtin_bit_cast(bf16x8, l_); }

// ---------------------------------------------------------------------------
// k_gemm_in: zA = X @ Wi^T + bi (f32 out), raw-f32 inputs split in-register,
// swapped-operand MFMA, 3-term split, split-K=2 across waves.
// grid: 256 blocks (slab = bid&127, ch = bid>>7), 512 threads.
// wave w: ct = w&3 (16-col tile), kh = w>>2 (K half; kh0 k<384 + bias,
// kh1 k>=384 + 784-tail). Cross-K reduce via LDS.
// ---------------------------------------------------------------------------
__global__ __launch_bounds__(512) void k_gemm_in(
        const float* __restrict__ X, const float* __restrict__ Wi,
        const float* __restrict__ bi, float* __restrict__ zA) {
    __shared__ f32x4 redS[4][64];
    const int tid  = threadIdx.x;
    const int w    = tid >> 6;
    const int lane = tid & 63;
    const int l15  = lane & 15;
    const int lq   = lane >> 4;
    const int slab = blockIdx.x & 127;
    const int ch   = blockIdx.x >> 7;
    const int ct   = w & 3;
    const int kh   = w >> 2;
    const int r0   = slab * 16;
    const int cb   = ch * 64 + ct * 16;
    const int colA = cb + l15;
    const int KD   = 784;

    const float* xp = &X[(long)(r0 + l15) * KD];
    const float* wp = &Wi[(long)colA * KD];

    f32x4 a0 = {0.f, 0.f, 0.f, 0.f};
    f32x4 a1 = {0.f, 0.f, 0.f, 0.f};
    f32x4 a2 = {0.f, 0.f, 0.f, 0.f};
    if (kh == 0) {
        float4 b4 = *(const float4*)&bi[cb + lq * 4];
        a0[0] = b4.x; a0[1] = b4.y; a0[2] = b4.z; a0[3] = b4.w;
    }

    const int kbase = kh ? 384 : 0;
    #pragma unroll 6
    for (int c = 0; c < 12; ++c) {
        const int k = kbase + c * 32 + lq * 8;
        float4 xa = *(const float4*)&xp[k];
        float4 xb = *(const float4*)&xp[k + 4];
        float4 wa = *(const float4*)&wp[k];
        float4 wb = *(const float4*)&wp[k + 4];
        bf16x8 ah, al, bh, bl;
        SPLIT8(xa, xb, ah, al)
        SPLIT8(wa, wb, bh, bl)
        a0 = MFMA(bh, ah, a0);     // Wh . xh
        a1 = MFMA(bh, al, a1);     // Wh . xl
        a2 = MFMA(bl, ah, a2);     // Wl . xh
    }
    if (kh) {   // tail k = 768..783 (valid lq<2)
        float4 z4 = make_float4(0.f, 0.f, 0.f, 0.f);
        float4 xa = z4, xb = z4, wa = z4, wb = z4;
        if (lq < 2) {
            const int k = 768 + lq * 8;
            xa = *(const float4*)&xp[k];
            xb = *(const float4*)&xp[k + 4];
            wa = *(const float4*)&wp[k];
            wb = *(const float4*)&wp[k + 4];
        }
        bf16x8 ah, al, bh, bl;
        SPLIT8(xa, xb, ah, al)
        SPLIT8(wa, wb, bh, bl)
        a0 = MFMA(bh, ah, a0);
        a1 = MFMA(bh, al, a1);
        a2 = MFMA(bl, ah, a2);
    }

    f32x4 r;
    #pragma unroll
    for (int i = 0; i < 4; ++i) r[i] = a0[i] + a1[i] + a2[i];

    if (kh) redS[ct][lane] = r;
    __syncthreads();
    if (!kh) {
        f32x4 o = redS[ct][lane];
        float4 st;
        st.x = r[0] + o[0]; st.y = r[1] + o[1];
        st.z = r[2] + o[2]; st.w = r[3] + o[3];
        *(float4*)&zA[(long)(r0 + l15) * U + cb + lq * 4] = st;
    }
}

// ---------------------------------------------------------------------------
// k_picard: Picard layers + output GEMM + softmax.
// grid: B/16 blocks, 512 threads (8 waves). Wave w owns cols 16w..16w+15.
// z in LDS as RTNE bf16 HI ONLY (halves LDS traffic; W stays 3-term in regs:
// zh.Wh + zh.Wl). Wb read as raw f32, split in-register once per layer.
// LDS z: byte(r,c) = r*256 + ((2c) ^ ((r&7)<<4))  XOR swizzle.
// ---------------------------------------------------------------------------
__global__ __launch_bounds__(512) void k_picard(
        const float* __restrict__ zA, const float* __restrict__ Wb,
        const float* __restrict__ Wo, const float* __restrict__ bo,
        float* __restrict__ Out, int L) {
    __shared__ unsigned short zhS[2][16 * U];   // 2 x 4 KB (double-buffered)

    const int tid  = threadIdx.x;
    const int w    = tid >> 6;
    const int lane = tid & 63;
    const int l15  = lane & 15;
    const int lq   = lane >> 4;
    const int r0   = blockIdx.x * 16;
    const int colA = w * 16 + l15;     // W row for A-frags (= output col)

    // x (z-lin) from k_gemm_in: lane l15 = batch row, reg i = col 16w+4lq+i
    float xf[4], zr[4];
    {
        float4 x4 = *(const float4*)&zA[(long)(r0 + l15) * U + w * 16 + lq * 4];
        xf[0] = x4.x; xf[1] = x4.y; xf[2] = x4.z; xf[3] = x4.w;
    }

    const int swz = (l15 & 7) << 4;
    int offA[4];
    #pragma unroll
    for (int ks = 0; ks < 4; ++ks)
        offA[ks] = l15 * 256 + ((64 * ks + 16 * lq) ^ swz);
    const int offWr = l15 * 256 + ((32 * w + 8 * lq) ^ swz);

    char* zhB = (char*)&zhS[0][0];

    for (int l = 0; l < L; ++l) {
        // layer weights: f32 -> 3-term split in registers (once per layer)
        bf16x8 whf[4], wlf[4];
        {
            const float* wrow = &Wb[((long)l * U + colA) * U];
            #pragma unroll
            for (int ks = 0; ks < 4; ++ks) {
                const int k = ks * 32 + lq * 8;
                float4 p = *(const float4*)&wrow[k];
                float4 q = *(const float4*)&wrow[k + 4];
                SPLIT8(p, q, whf[ks], wlf[ks])
            }
        }

        // z0 = tanh(x) -> buffer 0
        {
            #pragma unroll
            for (int i = 0; i < 4; ++i) zr[i] = tanh_fast(xf[i]);
            uint2 hh;
            hh.x = packrn(zr[0], zr[1]);
            hh.y = packrn(zr[2], zr[3]);
            *(uint2*)(zhB + offWr) = hh;
        }
        __syncthreads();

        #pragma unroll 2
        for (int it = 0; it < NIT; ++it) {
            const int cur = it & 1;
            const int nxt = cur ^ 1;
            bf16x8 zhf[4];
            #pragma unroll
            for (int ks = 0; ks < 4; ++ks)
                zhf[ks] = *(const bf16x8*)(zhB + cur * 4096 + offA[ks]);

            // 4 independent accumulator chains, depth 2
            f32x4 b0a = {xf[0], xf[1], xf[2], xf[3]};
            f32x4 b0b = {0.f, 0.f, 0.f, 0.f};
            f32x4 b1a = b0b, b1b = b0b;
            b0a = MFMA(whf[0], zhf[0], b0a);
            b1a = MFMA(wlf[0], zhf[0], b1a);
            b0b = MFMA(whf[2], zhf[2], b0b);
            b1b = MFMA(wlf[2], zhf[2], b1b);
            b0a = MFMA(whf[1], zhf[1], b0a);
            b1a = MFMA(wlf[1], zhf[1], b1a);
            b0b = MFMA(whf[3], zhf[3], b0b);
            b1b = MFMA(wlf[3], zhf[3], b1b);

            #pragma unroll
            for (int i = 0; i < 4; ++i)
                zr[i] = tanh_fast(b0a[i] + b0b[i] + b1a[i] + b1b[i]);
            uint2 hh;
            hh.x = packrn(zr[0], zr[1]);
            hh.y = packrn(zr[2], zr[3]);
            *(uint2*)(zhB + nxt * 4096 + offWr) = hh;
            __syncthreads();
        }
        #pragma unroll
        for (int i = 0; i < 4; ++i) xf[i] = zr[i];   // next layer input
    }
    // NIT even => final z in buffer 0

    // ---------------- output GEMM + softmax ----------------
    #pragma unroll
    for (int rr2 = 0; rr2 < 2; ++rr2) {
        const int rrow = 2 * w + rr2;
        const int o1 = rrow * 256 + ((lane * 2) ^ ((rrow & 7) << 4));
        const int o2 = rrow * 256 + (((lane + 64) * 2) ^ ((rrow & 7) << 4));
        const float zv0 = fromhi(*(const unsigned short*)(zhB + o1));
        const float zv1 = fromhi(*(const unsigned short*)(zhB + o2));
        float e[10];
        float m = -1e30f;
        #pragma unroll
        for (int o = 0; o < 10; ++o) {
            float p = zv0 * Wo[o * U + lane] + zv1 * Wo[o * U + 64 + lane];
            #pragma unroll
            for (int off = 32; off > 0; off >>= 1)
                p += __shfl_xor(p, off);
            p += bo[o];
            e[o] = p;
            m = fmaxf(m, p);
        }
        float s = 0.f;
        #pragma unroll
        for (int o = 0; o < 10; ++o) {
            e[o] = __expf(e[o] - m);
            s += e[o];
        }
        const float inv = 1.0f / s;
        float v = 0.f;
        #pragma unroll
        for (int o = 0; o < 10; ++o)
            if (lane == o) v = e[o] * inv;
        if (lane < 10) Out[(long)(r0 + rrow) * 10 + lane] = v;
    }
}

// ---------------------------------------------------------------------------
extern "C" void kernel_launch(void* const* d_in, const int* in_sizes, int n_in,
                              void* d_out, int out_size, void* d_ws, size_t ws_size,
                              hipStream_t stream) {
    const float* x  = (const float*)d_in[0];   // [B,784]
    const float* Wi = (const float*)d_in[1];   // [128,784]
    const float* bi = (const float*)d_in[2];   // [128]
    const float* Wb = (const float*)d_in[3];   // [L,128,128]
    const float* Wo = (const float*)d_in[4];   // [10,128]
    const float* bo = (const float*)d_in[5];   // [10]
    float* out = (float*)d_out;

    const int DIN = 784;
    const int B   = in_sizes[0] / DIN;             // 2048
    const int L   = in_sizes[3] / (U * U);         // 2

    float* zA = (float*)d_ws;                      // [B,U] f32

    k_gemm_in<<<256, 512, 0, stream>>>(x, Wi, bi, zA);
    k_picard<<<B / 16, 512, 0, stream>>>(zA, Wb, Wo, bo, out, L);
}

// Round 10
// 33.873 us; speedup vs baseline: 1.6676x; 1.0820x over previous
//
#include <hip/hip_runtime.h>
#include <math.h>

#define U 128
#define NIT 12   // fixed Picard iterations per layer (even); ρ≲0.5 measured across
                 // NIT∈{16,20,48} (absmax pinned at bf16-z quant floor 2e-3)

typedef __attribute__((ext_vector_type(8))) short bf16x8;
typedef __attribute__((ext_vector_type(4))) float f32x4;
typedef __attribute__((ext_vector_type(4))) unsigned int u32x4;

__device__ inline unsigned int pack2(float a, float b) {
    // low short = bf16(a) (truncated), high short = bf16(b)
    return (__float_as_uint(a) >> 16) | (__float_as_uint(b) & 0xFFFF0000u);
}
__device__ inline float lo_of(float a) {
    return a - __uint_as_float(__float_as_uint(a) & 0xFFFF0000u);
}
__device__ inline unsigned int packrn(float a, float b) {
    // RTNE pack (v_cvt_pk_bf16_f32): low = bf16_rn(a), high = bf16_rn(b)
    unsigned int r;
    asm("v_cvt_pk_bf16_f32 %0, %1, %2" : "=v"(r) : "v"(a), "v"(b));
    return r;
}
__device__ inline float fromhi(unsigned short h) {
    return __uint_as_float(((unsigned int)h) << 16);
}
__device__ inline float tanh_fast(float v) {
    float e = __expf(2.0f * v);
    return 1.0f - 2.0f / (e + 1.0f);
}
#define MFMA(A, B, C) __builtin_amdgcn_mfma_f32_16x16x32_bf16(A, B, C, 0, 0, 0)

// in-register f32 -> (trunc-bf16 hi, bf16 lo) split of 8 values
#define SPLIT8(P4, Q4, H, LO)                                              \
{   u32x4 h_, l_;                                                          \
    h_[0] = pack2(P4.x, P4.y); h_[1] = pack2(P4.z, P4.w);                  \
    h_[2] = pack2(Q4.x, Q4.y); h_[3] = pack2(Q4.z, Q4.w);                  \
    l_[0] = pack2(lo_of(P4.x), lo_of(P4.y));                               \
    l_[1] = pack2(lo_of(P4.z), lo_of(P4.w));                               \
    l_[2] = pack2(lo_of(Q4.x), lo_of(Q4.y));                               \
    l_[3] = pack2(lo_of(Q4.z), lo_of(Q4.w));                               \
    H  = __builtin_bit_cast(bf16x8, h_);                                   \
    LO = __builtin_bit_cast(bf16x8, l_); }

// ---------------------------------------------------------------------------
// k_gemm_in: zA = X @ Wi^T + bi (f32 out), raw-f32 inputs split in-register,
// swapped-operand MFMA, 3-term split, split-K=2 across waves. (unchanged R9)
// ---------------------------------------------------------------------------
__global__ __launch_bounds__(512) void k_gemm_in(
        const float* __restrict__ X, const float* __restrict__ Wi,
        const float* __restrict__ bi, float* __restrict__ zA) {
    __shared__ f32x4 redS[4][64];
    const int tid  = threadIdx.x;
    const int w    = tid >> 6;
    const int lane = tid & 63;
    const int l15  = lane & 15;
    const int lq   = lane >> 4;
    const int slab = blockIdx.x & 127;
    const int ch   = blockIdx.x >> 7;
    const int ct   = w & 3;
    const int kh   = w >> 2;
    const int r0   = slab * 16;
    const int cb   = ch * 64 + ct * 16;
    const int colA = cb + l15;
    const int KD   = 784;

    const float* xp = &X[(long)(r0 + l15) * KD];
    const float* wp = &Wi[(long)colA * KD];

    f32x4 a0 = {0.f, 0.f, 0.f, 0.f};
    f32x4 a1 = {0.f, 0.f, 0.f, 0.f};
    f32x4 a2 = {0.f, 0.f, 0.f, 0.f};
    if (kh == 0) {
        float4 b4 = *(const float4*)&bi[cb + lq * 4];
        a0[0] = b4.x; a0[1] = b4.y; a0[2] = b4.z; a0[3] = b4.w;
    }

    const int kbase = kh ? 384 : 0;
    #pragma unroll 6
    for (int c = 0; c < 12; ++c) {
        const int k = kbase + c * 32 + lq * 8;
        float4 xa = *(const float4*)&xp[k];
        float4 xb = *(const float4*)&xp[k + 4];
        float4 wa = *(const float4*)&wp[k];
        float4 wb = *(const float4*)&wp[k + 4];
        bf16x8 ah, al, bh, bl;
        SPLIT8(xa, xb, ah, al)
        SPLIT8(wa, wb, bh, bl)
        a0 = MFMA(bh, ah, a0);     // Wh . xh
        a1 = MFMA(bh, al, a1);     // Wh . xl
        a2 = MFMA(bl, ah, a2);     // Wl . xh
    }
    if (kh) {   // tail k = 768..783 (valid lq<2)
        float4 z4 = make_float4(0.f, 0.f, 0.f, 0.f);
        float4 xa = z4, xb = z4, wa = z4, wb = z4;
        if (lq < 2) {
            const int k = 768 + lq * 8;
            xa = *(const float4*)&xp[k];
            xb = *(const float4*)&xp[k + 4];
            wa = *(const float4*)&wp[k];
            wb = *(const float4*)&wp[k + 4];
        }
        bf16x8 ah, al, bh, bl;
        SPLIT8(xa, xb, ah, al)
        SPLIT8(wa, wb, bh, bl)
        a0 = MFMA(bh, ah, a0);
        a1 = MFMA(bh, al, a1);
        a2 = MFMA(bl, ah, a2);
    }

    f32x4 r;
    #pragma unroll
    for (int i = 0; i < 4; ++i) r[i] = a0[i] + a1[i] + a2[i];

    if (kh) redS[ct][lane] = r;
    __syncthreads();
    if (!kh) {
        f32x4 o = redS[ct][lane];
        float4 st;
        st.x = r[0] + o[0]; st.y = r[1] + o[1];
        st.z = r[2] + o[2]; st.w = r[3] + o[3];
        *(float4*)&zA[(long)(r0 + l15) * U + cb + lq * 4] = st;
    }
}

// ---------------------------------------------------------------------------
// k_picard: Picard layers + MFMA output GEMM + softmax.
// grid: B/16 blocks, 256 threads (4 waves). Wave w owns cols 32w..32w+31
// (TWO 16-col MFMA tiles) -> z-frags read ONCE per wave feed 2 tiles:
// halves LDS traffic vs 8-wave col-split. z in LDS as RTNE bf16 hi-only.
// LDS z: byte(r,c) = r*256 + ((2c) ^ ((r&7)<<4))  XOR swizzle.
// Phase 3: wave 0 computes softmax(z @ Wo^T + bo) via 2-term MFMA +
// 2-level shuffle reduce (classes padded 10->16).
// ---------------------------------------------------------------------------
__global__ __launch_bounds__(256) void k_picard(
        const float* __restrict__ zA, const float* __restrict__ Wb,
        const float* __restrict__ Wo, const float* __restrict__ bo,
        float* __restrict__ Out, int L) {
    __shared__ unsigned short zhS[2][16 * U];   // 2 x 4 KB (double-buffered)

    const int tid  = threadIdx.x;
    const int w    = tid >> 6;          // 0..3
    const int lane = tid & 63;
    const int l15  = lane & 15;
    const int lq   = lane >> 4;
    const int r0   = blockIdx.x * 16;

    // x (z-lin): lane l15 = batch row; regs: ct0 cols 32w+4lq..+3, ct1 +16
    float xf[8], zr[8];
    {
        const float* zrow = &zA[(long)(r0 + l15) * U + w * 32 + lq * 4];
        float4 x40 = *(const float4*)&zrow[0];
        float4 x41 = *(const float4*)&zrow[16];
        xf[0] = x40.x; xf[1] = x40.y; xf[2] = x40.z; xf[3] = x40.w;
        xf[4] = x41.x; xf[5] = x41.y; xf[6] = x41.z; xf[7] = x41.w;
    }

    const int swz = (l15 & 7) << 4;
    int offA[4];
    #pragma unroll
    for (int ks = 0; ks < 4; ++ks)
        offA[ks] = l15 * 256 + ((64 * ks + 16 * lq) ^ swz);
    const int offW0 = l15 * 256 + (((64 * w + 8 * lq)) ^ swz);        // ct0
    const int offW1 = l15 * 256 + (((64 * w + 32 + 8 * lq)) ^ swz);   // ct1

    char* zhB = (char*)&zhS[0][0];

    for (int l = 0; l < L; ++l) {
        // layer weights for both col-tiles: f32 -> 3-term split in registers
        bf16x8 whf[2][4], wlf[2][4];
        #pragma unroll
        for (int ct = 0; ct < 2; ++ct) {
            const int colA = w * 32 + ct * 16 + l15;
            const float* wrow = &Wb[((long)l * U + colA) * U];
            #pragma unroll
            for (int ks = 0; ks < 4; ++ks) {
                const int k = ks * 32 + lq * 8;
                float4 p = *(const float4*)&wrow[k];
                float4 q = *(const float4*)&wrow[k + 4];
                SPLIT8(p, q, whf[ct][ks], wlf[ct][ks])
            }
        }

        // z0 = tanh(x) -> buffer 0
        {
            #pragma unroll
            for (int i = 0; i < 8; ++i) zr[i] = tanh_fast(xf[i]);
            uint2 h0, h1;
            h0.x = packrn(zr[0], zr[1]); h0.y = packrn(zr[2], zr[3]);
            h1.x = packrn(zr[4], zr[5]); h1.y = packrn(zr[6], zr[7]);
            *(uint2*)(zhB + offW0) = h0;
            *(uint2*)(zhB + offW1) = h1;
        }
        __syncthreads();

        #pragma unroll 2
        for (int it = 0; it < NIT; ++it) {
            const int cur = it & 1;
            const int nxt = cur ^ 1;
            bf16x8 zhf[4];
            #pragma unroll
            for (int ks = 0; ks < 4; ++ks)
                zhf[ks] = *(const bf16x8*)(zhB + cur * 4096 + offA[ks]);

            // 8 independent chains (2 ct x {hi,lo} x 2 halves), depth 2
            f32x4 A0 = {xf[0], xf[1], xf[2], xf[3]};
            f32x4 Z4 = {0.f, 0.f, 0.f, 0.f};
            f32x4 A1 = Z4, A2 = Z4, A3 = Z4;
            f32x4 B0 = {xf[4], xf[5], xf[6], xf[7]};
            f32x4 B1 = Z4, B2 = Z4, B3 = Z4;
            A0 = MFMA(whf[0][0], zhf[0], A0);
            B0 = MFMA(whf[1][0], zhf[0], B0);
            A1 = MFMA(whf[0][2], zhf[2], A1);
            B1 = MFMA(whf[1][2], zhf[2], B1);
            A2 = MFMA(wlf[0][0], zhf[0], A2);
            B2 = MFMA(wlf[1][0], zhf[0], B2);
            A3 = MFMA(wlf[0][2], zhf[2], A3);
            B3 = MFMA(wlf[1][2], zhf[2], B3);
            A0 = MFMA(whf[0][1], zhf[1], A0);
            B0 = MFMA(whf[1][1], zhf[1], B0);
            A1 = MFMA(whf[0][3], zhf[3], A1);
            B1 = MFMA(whf[1][3], zhf[3], B1);
            A2 = MFMA(wlf[0][1], zhf[1], A2);
            B2 = MFMA(wlf[1][1], zhf[1], B2);
            A3 = MFMA(wlf[0][3], zhf[3], A3);
            B3 = MFMA(wlf[1][3], zhf[3], B3);

            #pragma unroll
            for (int i = 0; i < 4; ++i) {
                zr[i]     = tanh_fast(A0[i] + A1[i] + A2[i] + A3[i]);
                zr[4 + i] = tanh_fast(B0[i] + B1[i] + B2[i] + B3[i]);
            }
            uint2 h0, h1;
            h0.x = packrn(zr[0], zr[1]); h0.y = packrn(zr[2], zr[3]);
            h1.x = packrn(zr[4], zr[5]); h1.y = packrn(zr[6], zr[7]);
            *(uint2*)(zhB + nxt * 4096 + offW0) = h0;
            *(uint2*)(zhB + nxt * 4096 + offW1) = h1;
            __syncthreads();
        }
        #pragma unroll
        for (int i = 0; i < 8; ++i) xf[i] = zr[i];   // next layer input
    }
    // NIT even => final z in buffer 0

    // ---------------- Phase 3 (wave 0): out = softmax(z @ Wo^T + bo) -------
    if (w == 0) {
        // A-frag: Wo rows (classes, pad >=10 with zeros), 2-term split
        bf16x8 woh[4], wol[4];
        #pragma unroll
        for (int ks = 0; ks < 4; ++ks) {
            float4 p = make_float4(0.f, 0.f, 0.f, 0.f), q = p;
            if (l15 < 10) {
                const float* worow = &Wo[l15 * U + ks * 32 + lq * 8];
                p = *(const float4*)&worow[0];
                q = *(const float4*)&worow[4];
            }
            SPLIT8(p, q, woh[ks], wol[ks])
        }
        // B-frag: final z from buffer 0
        bf16x8 zf[4];
        #pragma unroll
        for (int ks = 0; ks < 4; ++ks)
            zf[ks] = *(const bf16x8*)(zhB + offA[ks]);

        f32x4 d0 = {0.f, 0.f, 0.f, 0.f};
        f32x4 d1 = d0;
        #pragma unroll
        for (int ks = 0; ks < 4; ++ks) {
            d0 = MFMA(woh[ks], zf[ks], d0);
            d1 = MFMA(wol[ks], zf[ks], d1);
        }
        // lane l15 = batch row, reg i -> class 4lq+i
        float lg[4];
        #pragma unroll
        for (int i = 0; i < 4; ++i) {
            const int c = 4 * lq + i;
            lg[i] = (c < 10) ? (d0[i] + d1[i] + bo[c]) : -1e30f;
        }
        float m = fmaxf(fmaxf(lg[0], lg[1]), fmaxf(lg[2], lg[3]));
        m = fmaxf(m, __shfl_xor(m, 16));
        m = fmaxf(m, __shfl_xor(m, 32));
        float e[4], s = 0.f;
        #pragma unroll
        for (int i = 0; i < 4; ++i) { e[i] = __expf(lg[i] - m); s += e[i]; }
        s += __shfl_xor(s, 16);
        s += __shfl_xor(s, 32);
        const float inv = 1.0f / s;
        #pragma unroll
        for (int i = 0; i < 4; ++i) {
            const int c = 4 * lq + i;
            if (c < 10) Out[(long)(r0 + l15) * 10 + c] = e[i] * inv;
        }
    }
}

// ---------------------------------------------------------------------------
extern "C" void kernel_launch(void* const* d_in, const int* in_sizes, int n_in,
                              void* d_out, int out_size, void* d_ws, size_t ws_size,
                              hipStream_t stream) {
    const float* x  = (const float*)d_in[0];   // [B,784]
    const float* Wi = (const float*)d_in[1];   // [128,784]
    const float* bi = (const float*)d_in[2];   // [128]
    const float* Wb = (const float*)d_in[3];   // [L,128,128]
    const float* Wo = (const float*)d_in[4];   // [10,128]
    const float* bo = (const float*)d_in[5];   // [10]
    float* out = (float*)d_out;

    const int DIN = 784;
    const int B   = in_sizes[0] / DIN;             // 2048
    const int L   = in_sizes[3] / (U * U);         // 2

    float* zA = (float*)d_ws;                      // [B,U] f32

    k_gemm_in<<<256, 512, 0, stream>>>(x, Wi, bi, zA);
    k_picard<<<B / 16, 256, 0, stream>>>(zA, Wb, Wo, bo, out, L);
}